// Round 14
// baseline (160.789 us; speedup 1.0000x reference)
//
#include <hip/hip_runtime.h>
#include <hip/hip_bf16.h>

#define F 128
#define NG 512

typedef __attribute__((ext_vector_type(8))) short s16x8;
typedef __attribute__((ext_vector_type(4))) float f32x4;

__device__ inline float bf2f(unsigned short u) {
    unsigned int x = ((unsigned int)u) << 16;
    return __builtin_bit_cast(float, x);
}
__device__ inline unsigned short f2bf(float f) {
    __hip_bfloat16 h = __float2bfloat16(f);
    return __builtin_bit_cast(unsigned short, h);
}
__device__ inline unsigned int pack16(float x, float y) {
    return (unsigned int)f2bf(x) | ((unsigned int)f2bf(y) << 16);
}

// async 16B global->LDS DMA: dest = lds_base + lane*16 (wave-uniform base)
typedef const __attribute__((address_space(1))) unsigned int guint;
typedef __attribute__((address_space(3))) unsigned int luint;
__device__ inline void stage16(const void* g, void* l) {
    __builtin_amdgcn_global_load_lds((guint*)g, (luint*)l, 16, 0, 0);
}

// build one bf16 A-fragment of S from one u32 of 8 nibble-counts:
// S[row][kbase+j] = alpha*cnt + (row==kbase+j)*(1-alpha)
__device__ inline s16x8 sfrag4(unsigned w, int kbase, int row, float alpha, float diagv) {
    s16x8 a;
    #pragma unroll
    for (int j = 0; j < 8; ++j) {
        float v = alpha * (float)((w >> (4 * j)) & 0xFu);
        if (kbase + j == row) v += diagv;
        a[j] = (short)f2bf(v);
    }
    return a;
}

// ---- prep: cast X (row+col major bf16) + shuffle weights + zero nibble counters ----
// blocks [0,512): X cast; [512,896): weight shuffle; [896,1408): zero cnt (8.39 MB)

__global__ __launch_bounds__(256) void prep_kernel(const float* __restrict__ X,
                                                   unsigned short* __restrict__ Xr,
                                                   unsigned short* __restrict__ Xc,
                                                   const float* __restrict__ W1,
                                                   const float* __restrict__ W2,
                                                   unsigned short* __restrict__ o1,
                                                   unsigned short* __restrict__ o2,
                                                   uint4* __restrict__ cntz,
                                                   unsigned int* __restrict__ donectr) {
    __shared__ unsigned short tile[64][F + 4];
    int tid = threadIdx.x;
    if (blockIdx.x < 512) {
        int g = blockIdx.x >> 3;
        int nt = blockIdx.x & 7;
        int node0 = nt * 64;
        const float* Xg = X + ((size_t)g * NG + node0) * F;
        unsigned short* Xrg = Xr + ((size_t)g * NG + node0) * F;
        #pragma unroll
        for (int u = tid; u < 64 * 32; u += 256) {
            int row = u >> 5, c4 = u & 31;
            float4 v = ((const float4*)(Xg + (size_t)row * F))[c4];
            unsigned short a0 = f2bf(v.x), a1 = f2bf(v.y), a2 = f2bf(v.z), a3 = f2bf(v.w);
            tile[row][c4 * 4 + 0] = a0;
            tile[row][c4 * 4 + 1] = a1;
            tile[row][c4 * 4 + 2] = a2;
            tile[row][c4 * 4 + 3] = a3;
            uint2 w;
            w.x = (unsigned int)a0 | ((unsigned int)a1 << 16);
            w.y = (unsigned int)a2 | ((unsigned int)a3 << 16);
            ((uint2*)(Xrg + (size_t)row * F))[c4] = w;
        }
        __syncthreads();
        unsigned short* Xcg = Xc + (size_t)g * F * NG;
        #pragma unroll
        for (int u = tid; u < F * 16; u += 256) {
            int f = u >> 4, nb = u & 15;
            int n0 = nb * 4;
            uint2 w;
            w.x = (unsigned int)tile[n0 + 0][f] | ((unsigned int)tile[n0 + 1][f] << 16);
            w.y = (unsigned int)tile[n0 + 2][f] | ((unsigned int)tile[n0 + 3][f] << 16);
            ((uint2*)(Xcg + (size_t)f * NG + node0))[nb] = w;
        }
    } else if (blockIdx.x < 896) {
        int t = (blockIdx.x - 512) * 256 + tid;   // [0, 98304)
        const float* W = (t < 49152) ? W1 : W2;
        unsigned short* o = (t < 49152) ? o1 : o2;
        int tt = (t < 49152) ? t : t - 49152;
        int j = tt & 7;
        int lane = (tt >> 3) & 63;
        int ct = (tt >> 9) & 7;
        int ks = tt >> 12;
        int k = ks * 32 + (lane >> 4) * 8 + j;
        int c = ct * 16 + (lane & 15);
        o[tt] = f2bf(W[(size_t)k * F + c]);
    } else {
        if (blockIdx.x == 896 && tid == 0) *donectr = 0;
        // zero 8.39 MB of nibble counts: 512 blocks x 256 thr x 4 uint4
        size_t base = (size_t)(blockIdx.x - 896) * 1024;
        uint4 z = {0u, 0u, 0u, 0u};
        #pragma unroll
        for (int i = 0; i < 4; ++i) cntz[base + i * 256 + tid] = z;
    }
}

// ---------------- edge-count scatter (u4 nibbles packed in u32 atomics) ----------------

__global__ void cnt_scatter_kernel(const int* __restrict__ src, const int* __restrict__ dst,
                                   unsigned int* __restrict__ cnt4, int E) {
    int e = blockIdx.x * blockDim.x + threadIdx.x;
    if (e >= E) return;
    int s = src[e], d = dst[e];
    size_t idx = ((size_t)s << 9) | (unsigned)(d & (NG - 1));
    atomicAdd(&cnt4[idx >> 3], 1u << ((idx & 7) * 4));
}

// ---------------- S-apply with B staged in LDS: Cc[g] = S[g] @ B[g] (16x16x32) ----------------
// S synthesized from nibble counts. Staging: async global_load_lds, pre-swizzled global src,
// linear LDS dest. Element [k][col] at Bs[col*512 + ((k>>3)^(col&7))*8 + (k&7)].
// XCD-chunked block swizzle: 4 sibling blocks of a graph share one XCD's L2.

__global__ __launch_bounds__(512) void sapply_kernel(
    const unsigned int* __restrict__ cnt4, const float* __restrict__ alphap,
    const unsigned short* __restrict__ Bc, unsigned short* __restrict__ Cc) {
    __shared__ unsigned short Bs[65536];   // 128 KB
    const int p = blockIdx.x;
    const int id = ((p & 7) << 5) | (p >> 3);
    const int g = id >> 2, rt = id & 3;
    const int tid = threadIdx.x, wave = tid >> 6, lane = tid & 63;
    const int l15 = lane & 15, hi = lane >> 4;
    const int lrow = wave * 16 + l15;
    const int row = rt * 128 + lrow;           // node index within graph
    const float alpha = *alphap;
    const float diagv = 1.0f - alpha;

    const unsigned short* Bcg = Bc + (size_t)g * F * NG;
    #pragma unroll
    for (int it = 0; it < 16; ++it) {
        int f = it * 8 + wave;                     // wave-uniform row (feature)
        stage16(Bcg + (size_t)f * NG + ((lane ^ (f & 7)) << 3), Bs + f * 512);
    }
    __syncthreads();

    f32x4 acc[8];
    #pragma unroll
    for (int ct = 0; ct < 8; ++ct) acc[ct] = (f32x4){0.f, 0.f, 0.f, 0.f};

    const unsigned int* crow = cnt4 + ((size_t)g * NG + row) * 64;   // 64 words per row
    const int bxor = l15 & 7;
    #pragma unroll 4
    for (int ks = 0; ks < 16; ++ks) {
        s16x8 a = sfrag4(crow[ks * 4 + hi], ks * 32 + hi * 8, row, alpha, diagv);
        #pragma unroll
        for (int ct = 0; ct < 8; ++ct) {
            int col = ct * 16 + l15;
            s16x8 b = *(const s16x8*)(Bs + col * 512 + ((((ks << 2) | hi) ^ bxor) << 3));
            acc[ct] = __builtin_amdgcn_mfma_f32_16x16x32_bf16(a, b, acc[ct], 0, 0, 0);
        }
    }

    // epilogue: col-major direct store only
    const int rloc = wave * 16 + (hi << 2);
    unsigned short* Ccg = Cc + (size_t)g * F * NG + rt * 128 + rloc;
    #pragma unroll
    for (int ct = 0; ct < 8; ++ct) {
        int col = ct * 16 + l15;
        uint2 w;
        w.x = pack16(acc[ct][0], acc[ct][1]);
        w.y = pack16(acc[ct][2], acc[ct][3]);
        *(uint2*)(Ccg + (size_t)col * NG) = w;
    }
}

// ---------------- fused: t2 = S@Bc (LDS-staged B) -> t2 tile in LDS -> conv ----------------
// conv A1 (t1) fragments are captured from the staged Bs into registers before the
// t2 tile overwrites it. A0 fragments from row-major global (coalesced, L2-hot).
// WRITE_H=1: h -> Hr+Hc. WRITE_H=0: col max -> pooledp; last block computes head.

template <int WRITE_H>
__global__ __launch_bounds__(512) void fused_conv_kernel(
    const unsigned int* __restrict__ cnt4, const float* __restrict__ alphap,
    const unsigned short* __restrict__ Bc, const unsigned short* __restrict__ A0,
    const unsigned short* __restrict__ Wswz, const float* __restrict__ bias,
    unsigned short* __restrict__ Hr, unsigned short* __restrict__ Hc,
    float* __restrict__ pooledp, unsigned int* __restrict__ donectr,
    const float* __restrict__ Wout, const float* __restrict__ bout,
    float* __restrict__ outp) {
    __shared__ unsigned short Bs[65536];   // 128 KB; B stage -> t2 tile [128][136] -> epilogue
    const int p = blockIdx.x;
    const int id = ((p & 7) << 5) | (p >> 3);
    const int g = id >> 2, rt = id & 3;
    const int tid = threadIdx.x, wave = tid >> 6, lane = tid & 63;
    const int l15 = lane & 15, hi = lane >> 4;
    const int lrow = wave * 16 + l15;
    const int row = rt * 128 + lrow;
    const float alpha = *alphap;
    const float diagv = 1.0f - alpha;

    const unsigned short* Bcg = Bc + (size_t)g * F * NG;
    #pragma unroll
    for (int it = 0; it < 16; ++it) {
        int f = it * 8 + wave;
        stage16(Bcg + (size_t)f * NG + ((lane ^ (f & 7)) << 3), Bs + f * 512);
    }
    __syncthreads();

    // ---- S-phase: t2 tile = S(rows) @ B ----
    f32x4 sacc[8];
    #pragma unroll
    for (int ct = 0; ct < 8; ++ct) sacc[ct] = (f32x4){0.f, 0.f, 0.f, 0.f};
    {
        const unsigned int* crow = cnt4 + ((size_t)g * NG + row) * 64;
        const int bxor = l15 & 7;
        #pragma unroll 4
        for (int ks = 0; ks < 16; ++ks) {
            s16x8 a = sfrag4(crow[ks * 4 + hi], ks * 32 + hi * 8, row, alpha, diagv);
            #pragma unroll
            for (int ct = 0; ct < 8; ++ct) {
                int col = ct * 16 + l15;
                s16x8 b = *(const s16x8*)(Bs + col * 512 + ((((ks << 2) | hi) ^ bxor) << 3));
                sacc[ct] = __builtin_amdgcn_mfma_f32_16x16x32_bf16(a, b, sacc[ct], 0, 0, 0);
            }
        }
    }

    // ---- capture conv A1 (t1) fragments from Bs before it's overwritten ----
    // t1[row][f0+j] = Bs[(f0+j)*512 + ((row>>3)^j)*8 + (row&7)]   (f0 multiple of 8)
    s16x8 a1f[4];
    #pragma unroll
    for (int kk = 0; kk < 4; ++kk) {
        int f0 = kk * 32 + hi * 8;
        s16x8 t;
        #pragma unroll
        for (int j = 0; j < 8; ++j)
            t[j] = (short)Bs[(f0 + j) * 512 + (((row >> 3) ^ j) << 3) + (row & 7)];
        a1f[kk] = t;
    }
    __syncthreads();   // B reads + captures complete; reuse Bs[0..17408) as t2 tile [128][136]

    {
        int rloc = wave * 16 + (hi << 2);
        #pragma unroll
        for (int ct = 0; ct < 8; ++ct) {
            int col = ct * 16 + l15;
            #pragma unroll
            for (int r = 0; r < 4; ++r)
                Bs[(rloc + r) * 136 + col] = f2bf(sacc[ct][r]);
        }
    }
    __syncthreads();

    // ---- conv phase: h = A0@W0 + t1@W1 + t2@W2 ----
    f32x4 acc[8];
    #pragma unroll
    for (int ct = 0; ct < 8; ++ct) acc[ct] = (f32x4){0.f, 0.f, 0.f, 0.f};
    const int arow = id * 128 + lrow;
    #pragma unroll
    for (int ks = 0; ks < 12; ++ks) {
        s16x8 a;
        if (ks < 4) {
            a = *(const s16x8*)(A0 + (size_t)arow * F + ks * 32 + hi * 8);
        } else if (ks < 8) {
            a = a1f[ks - 4];
        } else {
            a = *(const s16x8*)(Bs + lrow * 136 + (ks - 8) * 32 + hi * 8);
        }
        const unsigned short* wb = Wswz + ((size_t)ks * 512 + lane) * 8;
        #pragma unroll
        for (int ct = 0; ct < 8; ++ct) {
            s16x8 b = *(const s16x8*)(wb + (size_t)ct * 512);
            acc[ct] = __builtin_amdgcn_mfma_f32_16x16x32_bf16(a, b, acc[ct], 0, 0, 0);
        }
    }

    const int rloc = wave * 16 + (hi << 2);
    if (WRITE_H) {
        unsigned short* OutS = Bs + 40960;   // disjoint from t2 tile [0,17408)
        #pragma unroll
        for (int ct = 0; ct < 8; ++ct) {
            int col = ct * 16 + l15;
            float b = bias[col];
            float v0 = fmaxf(acc[ct][0] + b, 0.f);
            float v1 = fmaxf(acc[ct][1] + b, 0.f);
            float v2 = fmaxf(acc[ct][2] + b, 0.f);
            float v3 = fmaxf(acc[ct][3] + b, 0.f);
            uint2 w;
            w.x = pack16(v0, v1);
            w.y = pack16(v2, v3);
            *(uint2*)(Hc + (size_t)g * F * NG + (size_t)col * NG + rt * 128 + rloc) = w;
            OutS[(rloc + 0) * F + col] = f2bf(v0);
            OutS[(rloc + 1) * F + col] = f2bf(v1);
            OutS[(rloc + 2) * F + col] = f2bf(v2);
            OutS[(rloc + 3) * F + col] = f2bf(v3);
        }
        __syncthreads();
        uint4* o4 = (uint4*)(Hr + ((size_t)g * NG + rt * 128) * F);
        const uint4* s4 = (const uint4*)OutS;
        #pragma unroll
        for (int u = tid; u < 128 * F / 8; u += 512) o4[u] = s4[u];
    } else {
        __syncthreads();   // t2-tile reads done before aliasing with wmax
        float* wmax = (float*)Bs;
        #pragma unroll
        for (int ct = 0; ct < 8; ++ct) {
            int col = ct * 16 + l15;
            float b = bias[col];
            float m = fmaxf(fmaxf(acc[ct][0], acc[ct][1]), fmaxf(acc[ct][2], acc[ct][3]));
            m = fmaxf(m + b, 0.f);
            m = fmaxf(m, __shfl_xor(m, 16));
            m = fmaxf(m, __shfl_xor(m, 32));
            if (lane < 16) wmax[wave * F + col] = m;
        }
        __syncthreads();
        if (tid < F) {
            float m = wmax[tid];
            #pragma unroll
            for (int w = 1; w < 8; ++w) m = fmaxf(m, wmax[w * F + tid]);
            pooledp[((size_t)rt * 64 + g) * F + tid] = m;
        }
        // ---- last block computes the output head ----
        __threadfence();
        __syncthreads();
        unsigned int* flagp = (unsigned int*)Bs;
        if (tid == 0) {
            unsigned int old = __hip_atomic_fetch_add(donectr, 1u, __ATOMIC_ACQ_REL,
                                                      __HIP_MEMORY_SCOPE_AGENT);
            flagp[0] = (old == (unsigned)(gridDim.x - 1)) ? 1u : 0u;
        }
        __syncthreads();
        if (flagp[0]) {
            __threadfence();
            int b = tid >> 3;
            int og = (tid & 7) * 8;
            float acch[8];
            #pragma unroll
            for (int o = 0; o < 8; ++o) acch[o] = bout[og + o];
            for (int k = 0; k < F; ++k) {
                float pm = pooledp[(size_t)b * F + k];
                pm = fmaxf(pm, pooledp[(size_t)(64 + b) * F + k]);
                pm = fmaxf(pm, pooledp[(size_t)(128 + b) * F + k]);
                pm = fmaxf(pm, pooledp[(size_t)(192 + b) * F + k]);
                const float* wr = Wout + (size_t)k * 64 + og;
                #pragma unroll
                for (int o = 0; o < 8; ++o) acch[o] += pm * wr[o];
            }
            #pragma unroll
            for (int o = 0; o < 8; ++o) outp[(size_t)b * 64 + og + o] = acch[o];
        }
    }
}

// ---------------- launch ----------------

extern "C" void kernel_launch(void* const* d_in, const int* in_sizes, int n_in,
                              void* d_out, int out_size, void* d_ws, size_t ws_size,
                              hipStream_t stream) {
    const float* X     = (const float*)d_in[0];
    const int*   ei    = (const int*)d_in[2];
    const float* W1    = (const float*)d_in[3];
    const float* b1    = (const float*)d_in[4];
    const float* W2    = (const float*)d_in[5];
    const float* b2    = (const float*)d_in[6];
    const float* Wout  = (const float*)d_in[7];
    const float* bout  = (const float*)d_in[8];
    const float* alpha = (const float*)d_in[9];

    const int N = in_sizes[0] / F;   // 32768
    const int E = in_sizes[2] / 2;   // 524288
    const int Bg = N / NG;           // 64

    const int* srcv = ei;
    const int* dstv = ei + E;

    char* ws = (char*)d_ws;
    const size_t CBYTES = (size_t)Bg * NG * NG / 2;   // 8.39 MB (u4 counts, lives all run)
    const size_t PBYTES = (size_t)N * F * 2;          // 8.39 MB

    unsigned int* cnt4 = (unsigned int*)ws;
    unsigned short* P0 = (unsigned short*)(ws + CBYTES);               // Xr -> h1r
    unsigned short* P1 = (unsigned short*)(ws + CBYTES + PBYTES);      // Xc -> h1c
    unsigned short* P3 = (unsigned short*)(ws + CBYTES + 2 * PBYTES);  // t1c / u1c
    char* tail = ws + CBYTES + 3 * PBYTES;
    unsigned short* Wswz1 = (unsigned short*)tail;
    unsigned short* Wswz2 = Wswz1 + (size_t)3 * F * F;
    float* pooledp = (float*)(Wswz2 + (size_t)3 * F * F);             // [4][64][128]
    unsigned int* donectr = (unsigned int*)(pooledp + 4 * 64 * F);

    // prep: cast X + shuffle weights + zero cnt + zero donectr (no in-graph memsets)
    prep_kernel<<<1408, 256, 0, stream>>>(X, P0, P1, W1, W2, Wswz1, Wswz2, (uint4*)cnt4, donectr);

    // edge-count scatter (nibbles)
    cnt_scatter_kernel<<<(E + 255) / 256, 256, 0, stream>>>(srcv, dstv, cnt4, E);

    // layer 1: t1c = S@X ; h1 = relu(X@W0 + t1@W1 + (S@t1)@W2 + b1)
    sapply_kernel<<<Bg * 4, 512, 0, stream>>>(cnt4, alpha, P1, P3);
    fused_conv_kernel<1><<<Bg * 4, 512, 0, stream>>>(cnt4, alpha, P3, P0, Wswz1, b1, P0, P1,
                                                     nullptr, nullptr, nullptr, nullptr, nullptr);

    // layer 2: u1c = S@h1 ; pooled colmax + last-block output head
    sapply_kernel<<<Bg * 4, 512, 0, stream>>>(cnt4, alpha, P1, P3);
    fused_conv_kernel<0><<<Bg * 4, 512, 0, stream>>>(cnt4, alpha, P3, P0, Wswz2, b2, nullptr,
                                                     nullptr, pooledp, donectr, Wout, bout,
                                                     (float*)d_out);
}

// Round 15
// 110.494 us; speedup vs baseline: 1.4552x; 1.4552x over previous
//
#include <hip/hip_runtime.h>
#include <hip/hip_bf16.h>

#define F 128
#define NG 512

typedef __attribute__((ext_vector_type(8))) short s16x8;
typedef __attribute__((ext_vector_type(4))) float f32x4;

__device__ inline float bf2f(unsigned short u) {
    unsigned int x = ((unsigned int)u) << 16;
    return __builtin_bit_cast(float, x);
}
__device__ inline unsigned short f2bf(float f) {
    __hip_bfloat16 h = __float2bfloat16(f);
    return __builtin_bit_cast(unsigned short, h);
}
__device__ inline unsigned int pack16(float x, float y) {
    return (unsigned int)f2bf(x) | ((unsigned int)f2bf(y) << 16);
}

// async 16B global->LDS DMA: dest = lds_base + lane*16 (wave-uniform base)
typedef const __attribute__((address_space(1))) unsigned int guint;
typedef __attribute__((address_space(3))) unsigned int luint;
__device__ inline void stage16(const void* g, void* l) {
    __builtin_amdgcn_global_load_lds((guint*)g, (luint*)l, 16, 0, 0);
}

// build one bf16 A-fragment of S from one u32 of 8 nibble-counts:
// S[row][kbase+j] = alpha*cnt + (row==kbase+j)*(1-alpha)
__device__ inline s16x8 sfrag4(unsigned w, int kbase, int row, float alpha, float diagv) {
    s16x8 a;
    #pragma unroll
    for (int j = 0; j < 8; ++j) {
        float v = alpha * (float)((w >> (4 * j)) & 0xFu);
        if (kbase + j == row) v += diagv;
        a[j] = (short)f2bf(v);
    }
    return a;
}

// ---- prep: cast X (row+col major bf16) + shuffle weights + zero nibble counters ----
// blocks [0,512): X cast; [512,896): weight shuffle; [896,1408): zero cnt (8.39 MB)

__global__ __launch_bounds__(256) void prep_kernel(const float* __restrict__ X,
                                                   unsigned short* __restrict__ Xr,
                                                   unsigned short* __restrict__ Xc,
                                                   const float* __restrict__ W1,
                                                   const float* __restrict__ W2,
                                                   unsigned short* __restrict__ o1,
                                                   unsigned short* __restrict__ o2,
                                                   uint4* __restrict__ cntz) {
    __shared__ unsigned short tile[64][F + 4];
    int tid = threadIdx.x;
    if (blockIdx.x < 512) {
        int g = blockIdx.x >> 3;
        int nt = blockIdx.x & 7;
        int node0 = nt * 64;
        const float* Xg = X + ((size_t)g * NG + node0) * F;
        unsigned short* Xrg = Xr + ((size_t)g * NG + node0) * F;
        #pragma unroll
        for (int u = tid; u < 64 * 32; u += 256) {
            int row = u >> 5, c4 = u & 31;
            float4 v = ((const float4*)(Xg + (size_t)row * F))[c4];
            unsigned short a0 = f2bf(v.x), a1 = f2bf(v.y), a2 = f2bf(v.z), a3 = f2bf(v.w);
            tile[row][c4 * 4 + 0] = a0;
            tile[row][c4 * 4 + 1] = a1;
            tile[row][c4 * 4 + 2] = a2;
            tile[row][c4 * 4 + 3] = a3;
            uint2 w;
            w.x = (unsigned int)a0 | ((unsigned int)a1 << 16);
            w.y = (unsigned int)a2 | ((unsigned int)a3 << 16);
            ((uint2*)(Xrg + (size_t)row * F))[c4] = w;
        }
        __syncthreads();
        unsigned short* Xcg = Xc + (size_t)g * F * NG;
        #pragma unroll
        for (int u = tid; u < F * 16; u += 256) {
            int f = u >> 4, nb = u & 15;
            int n0 = nb * 4;
            uint2 w;
            w.x = (unsigned int)tile[n0 + 0][f] | ((unsigned int)tile[n0 + 1][f] << 16);
            w.y = (unsigned int)tile[n0 + 2][f] | ((unsigned int)tile[n0 + 3][f] << 16);
            ((uint2*)(Xcg + (size_t)f * NG + node0))[nb] = w;
        }
    } else if (blockIdx.x < 896) {
        int t = (blockIdx.x - 512) * 256 + tid;   // [0, 98304)
        const float* W = (t < 49152) ? W1 : W2;
        unsigned short* o = (t < 49152) ? o1 : o2;
        int tt = (t < 49152) ? t : t - 49152;
        int j = tt & 7;
        int lane = (tt >> 3) & 63;
        int ct = (tt >> 9) & 7;
        int ks = tt >> 12;
        int k = ks * 32 + (lane >> 4) * 8 + j;
        int c = ct * 16 + (lane & 15);
        o[tt] = f2bf(W[(size_t)k * F + c]);
    } else {
        // zero 8.39 MB of nibble counts: 512 blocks x 256 thr x 4 uint4
        size_t base = (size_t)(blockIdx.x - 896) * 1024;
        uint4 z = {0u, 0u, 0u, 0u};
        #pragma unroll
        for (int i = 0; i < 4; ++i) cntz[base + i * 256 + tid] = z;
    }
}

// ---------------- edge-count scatter (u4 nibbles packed in u32 atomics) ----------------

__global__ void cnt_scatter_kernel(const int* __restrict__ src, const int* __restrict__ dst,
                                   unsigned int* __restrict__ cnt4, int E) {
    int e = blockIdx.x * blockDim.x + threadIdx.x;
    if (e >= E) return;
    int s = src[e], d = dst[e];
    size_t idx = ((size_t)s << 9) | (unsigned)(d & (NG - 1));
    atomicAdd(&cnt4[idx >> 3], 1u << ((idx & 7) * 4));
}

// ---------------- S-apply with B staged in LDS: Cc[g] = S[g] @ B[g] (16x16x32) ----------------
// S synthesized from nibble counts. Staging: async global_load_lds, pre-swizzled global src,
// linear LDS dest. Element [k][col] at Bs[col*512 + ((k>>3)^(col&7))*8 + (k&7)].
// XCD-chunked block swizzle: 4 sibling blocks of a graph share one XCD's L2.

__global__ __launch_bounds__(512) void sapply_kernel(
    const unsigned int* __restrict__ cnt4, const float* __restrict__ alphap,
    const unsigned short* __restrict__ Bc, unsigned short* __restrict__ Cc) {
    __shared__ unsigned short Bs[65536];   // 128 KB
    const int p = blockIdx.x;
    const int id = ((p & 7) << 5) | (p >> 3);
    const int g = id >> 2, rt = id & 3;
    const int tid = threadIdx.x, wave = tid >> 6, lane = tid & 63;
    const int l15 = lane & 15, hi = lane >> 4;
    const int lrow = wave * 16 + l15;
    const int row = rt * 128 + lrow;           // node index within graph
    const float alpha = *alphap;
    const float diagv = 1.0f - alpha;

    const unsigned short* Bcg = Bc + (size_t)g * F * NG;
    #pragma unroll
    for (int it = 0; it < 16; ++it) {
        int f = it * 8 + wave;                     // wave-uniform row (feature)
        stage16(Bcg + (size_t)f * NG + ((lane ^ (f & 7)) << 3), Bs + f * 512);
    }
    __syncthreads();

    f32x4 acc[8];
    #pragma unroll
    for (int ct = 0; ct < 8; ++ct) acc[ct] = (f32x4){0.f, 0.f, 0.f, 0.f};

    const unsigned int* crow = cnt4 + ((size_t)g * NG + row) * 64;   // 64 words per row
    const int bxor = l15 & 7;
    #pragma unroll 4
    for (int ks = 0; ks < 16; ++ks) {
        s16x8 a = sfrag4(crow[ks * 4 + hi], ks * 32 + hi * 8, row, alpha, diagv);
        #pragma unroll
        for (int ct = 0; ct < 8; ++ct) {
            int col = ct * 16 + l15;
            s16x8 b = *(const s16x8*)(Bs + col * 512 + ((((ks << 2) | hi) ^ bxor) << 3));
            acc[ct] = __builtin_amdgcn_mfma_f32_16x16x32_bf16(a, b, acc[ct], 0, 0, 0);
        }
    }

    // epilogue: col-major direct store only
    const int rloc = wave * 16 + (hi << 2);
    unsigned short* Ccg = Cc + (size_t)g * F * NG + rt * 128 + rloc;
    #pragma unroll
    for (int ct = 0; ct < 8; ++ct) {
        int col = ct * 16 + l15;
        uint2 w;
        w.x = pack16(acc[ct][0], acc[ct][1]);
        w.y = pack16(acc[ct][2], acc[ct][3]);
        *(uint2*)(Ccg + (size_t)col * NG) = w;
    }
}

// ---------------- fused: t2 = S@Bc (LDS-staged B) -> t2 tile in LDS -> conv ----------------
// conv A1 (t1) fragments are captured from the staged Bs into registers before the
// t2 tile overwrites it. A0 fragments from row-major global (coalesced, L2-hot).
// WRITE_H=1: h -> Hr+Hc. WRITE_H=0: col max -> pooledp.

template <int WRITE_H>
__global__ __launch_bounds__(512) void fused_conv_kernel(
    const unsigned int* __restrict__ cnt4, const float* __restrict__ alphap,
    const unsigned short* __restrict__ Bc, const unsigned short* __restrict__ A0,
    const unsigned short* __restrict__ Wswz, const float* __restrict__ bias,
    unsigned short* __restrict__ Hr, unsigned short* __restrict__ Hc,
    float* __restrict__ pooledp) {
    __shared__ unsigned short Bs[65536];   // 128 KB; B stage -> t2 tile [128][136] -> epilogue
    const int p = blockIdx.x;
    const int id = ((p & 7) << 5) | (p >> 3);
    const int g = id >> 2, rt = id & 3;
    const int tid = threadIdx.x, wave = tid >> 6, lane = tid & 63;
    const int l15 = lane & 15, hi = lane >> 4;
    const int lrow = wave * 16 + l15;
    const int row = rt * 128 + lrow;
    const float alpha = *alphap;
    const float diagv = 1.0f - alpha;

    const unsigned short* Bcg = Bc + (size_t)g * F * NG;
    #pragma unroll
    for (int it = 0; it < 16; ++it) {
        int f = it * 8 + wave;
        stage16(Bcg + (size_t)f * NG + ((lane ^ (f & 7)) << 3), Bs + f * 512);
    }
    __syncthreads();

    // ---- S-phase: t2 tile = S(rows) @ B ----
    f32x4 sacc[8];
    #pragma unroll
    for (int ct = 0; ct < 8; ++ct) sacc[ct] = (f32x4){0.f, 0.f, 0.f, 0.f};
    {
        const unsigned int* crow = cnt4 + ((size_t)g * NG + row) * 64;
        const int bxor = l15 & 7;
        #pragma unroll 4
        for (int ks = 0; ks < 16; ++ks) {
            s16x8 a = sfrag4(crow[ks * 4 + hi], ks * 32 + hi * 8, row, alpha, diagv);
            #pragma unroll
            for (int ct = 0; ct < 8; ++ct) {
                int col = ct * 16 + l15;
                s16x8 b = *(const s16x8*)(Bs + col * 512 + ((((ks << 2) | hi) ^ bxor) << 3));
                sacc[ct] = __builtin_amdgcn_mfma_f32_16x16x32_bf16(a, b, sacc[ct], 0, 0, 0);
            }
        }
    }

    // ---- capture conv A1 (t1) fragments from Bs before it's overwritten ----
    // t1[row][f0+j] = Bs[(f0+j)*512 + ((row>>3)^j)*8 + (row&7)]   (f0 multiple of 8)
    s16x8 a1f[4];
    #pragma unroll
    for (int kk = 0; kk < 4; ++kk) {
        int f0 = kk * 32 + hi * 8;
        s16x8 t;
        #pragma unroll
        for (int j = 0; j < 8; ++j)
            t[j] = (short)Bs[(f0 + j) * 512 + (((row >> 3) ^ j) << 3) + (row & 7)];
        a1f[kk] = t;
    }
    __syncthreads();   // B reads + captures complete; reuse Bs[0..17408) as t2 tile [128][136]

    {
        int rloc = wave * 16 + (hi << 2);
        #pragma unroll
        for (int ct = 0; ct < 8; ++ct) {
            int col = ct * 16 + l15;
            #pragma unroll
            for (int r = 0; r < 4; ++r)
                Bs[(rloc + r) * 136 + col] = f2bf(sacc[ct][r]);
        }
    }
    __syncthreads();

    // ---- conv phase: h = A0@W0 + t1@W1 + t2@W2 ----
    f32x4 acc[8];
    #pragma unroll
    for (int ct = 0; ct < 8; ++ct) acc[ct] = (f32x4){0.f, 0.f, 0.f, 0.f};
    const int arow = id * 128 + lrow;
    #pragma unroll
    for (int ks = 0; ks < 12; ++ks) {
        s16x8 a;
        if (ks < 4) {
            a = *(const s16x8*)(A0 + (size_t)arow * F + ks * 32 + hi * 8);
        } else if (ks < 8) {
            a = a1f[ks - 4];
        } else {
            a = *(const s16x8*)(Bs + lrow * 136 + (ks - 8) * 32 + hi * 8);
        }
        const unsigned short* wb = Wswz + ((size_t)ks * 512 + lane) * 8;
        #pragma unroll
        for (int ct = 0; ct < 8; ++ct) {
            s16x8 b = *(const s16x8*)(wb + (size_t)ct * 512);
            acc[ct] = __builtin_amdgcn_mfma_f32_16x16x32_bf16(a, b, acc[ct], 0, 0, 0);
        }
    }

    const int rloc = wave * 16 + (hi << 2);
    if (WRITE_H) {
        unsigned short* OutS = Bs + 40960;   // disjoint from t2 tile [0,17408)
        #pragma unroll
        for (int ct = 0; ct < 8; ++ct) {
            int col = ct * 16 + l15;
            float b = bias[col];
            float v0 = fmaxf(acc[ct][0] + b, 0.f);
            float v1 = fmaxf(acc[ct][1] + b, 0.f);
            float v2 = fmaxf(acc[ct][2] + b, 0.f);
            float v3 = fmaxf(acc[ct][3] + b, 0.f);
            uint2 w;
            w.x = pack16(v0, v1);
            w.y = pack16(v2, v3);
            *(uint2*)(Hc + (size_t)g * F * NG + (size_t)col * NG + rt * 128 + rloc) = w;
            OutS[(rloc + 0) * F + col] = f2bf(v0);
            OutS[(rloc + 1) * F + col] = f2bf(v1);
            OutS[(rloc + 2) * F + col] = f2bf(v2);
            OutS[(rloc + 3) * F + col] = f2bf(v3);
        }
        __syncthreads();
        uint4* o4 = (uint4*)(Hr + ((size_t)g * NG + rt * 128) * F);
        const uint4* s4 = (const uint4*)OutS;
        #pragma unroll
        for (int u = tid; u < 128 * F / 8; u += 512) o4[u] = s4[u];
    } else {
        __syncthreads();   // t2-tile reads done before aliasing with wmax
        float* wmax = (float*)Bs;
        #pragma unroll
        for (int ct = 0; ct < 8; ++ct) {
            int col = ct * 16 + l15;
            float b = bias[col];
            float m = fmaxf(fmaxf(acc[ct][0], acc[ct][1]), fmaxf(acc[ct][2], acc[ct][3]));
            m = fmaxf(m + b, 0.f);
            m = fmaxf(m, __shfl_xor(m, 16));
            m = fmaxf(m, __shfl_xor(m, 32));
            if (lane < 16) wmax[wave * F + col] = m;
        }
        __syncthreads();
        if (tid < F) {
            float m = wmax[tid];
            #pragma unroll
            for (int w = 1; w < 8; ++w) m = fmaxf(m, wmax[w * F + tid]);
            pooledp[((size_t)rt * 64 + g) * F + tid] = m;
        }
    }
}

// ---------------- output head: pooled = max over 4 partials; out = pooled @ Wout + bout ----

__global__ __launch_bounds__(64) void out_gemm_kernel(const float* __restrict__ pooledp,
                                                      const float* __restrict__ Wout,
                                                      const float* __restrict__ bout,
                                                      float* __restrict__ out) {
    __shared__ float p[F];
    int b = blockIdx.x, t = threadIdx.x;
    #pragma unroll
    for (int c = t; c < F; c += 64) {
        float m = pooledp[(size_t)b * F + c];
        m = fmaxf(m, pooledp[((size_t)64 + b) * F + c]);
        m = fmaxf(m, pooledp[((size_t)128 + b) * F + c]);
        m = fmaxf(m, pooledp[((size_t)192 + b) * F + c]);
        p[c] = m;
    }
    __syncthreads();
    float acc = bout[t];
    #pragma unroll 8
    for (int k = 0; k < F; ++k) acc += p[k] * Wout[k * 64 + t];
    out[(size_t)b * 64 + t] = acc;
}

// ---------------- launch ----------------

extern "C" void kernel_launch(void* const* d_in, const int* in_sizes, int n_in,
                              void* d_out, int out_size, void* d_ws, size_t ws_size,
                              hipStream_t stream) {
    const float* X     = (const float*)d_in[0];
    const int*   ei    = (const int*)d_in[2];
    const float* W1    = (const float*)d_in[3];
    const float* b1    = (const float*)d_in[4];
    const float* W2    = (const float*)d_in[5];
    const float* b2    = (const float*)d_in[6];
    const float* Wout  = (const float*)d_in[7];
    const float* bout  = (const float*)d_in[8];
    const float* alpha = (const float*)d_in[9];

    const int N = in_sizes[0] / F;   // 32768
    const int E = in_sizes[2] / 2;   // 524288
    const int Bg = N / NG;           // 64

    const int* srcv = ei;
    const int* dstv = ei + E;

    char* ws = (char*)d_ws;
    const size_t CBYTES = (size_t)Bg * NG * NG / 2;   // 8.39 MB (u4 counts, lives all run)
    const size_t PBYTES = (size_t)N * F * 2;          // 8.39 MB

    unsigned int* cnt4 = (unsigned int*)ws;
    unsigned short* P0 = (unsigned short*)(ws + CBYTES);               // Xr -> h1r
    unsigned short* P1 = (unsigned short*)(ws + CBYTES + PBYTES);      // Xc -> h1c
    unsigned short* P3 = (unsigned short*)(ws + CBYTES + 2 * PBYTES);  // t1c / u1c
    char* tail = ws + CBYTES + 3 * PBYTES;
    unsigned short* Wswz1 = (unsigned short*)tail;
    unsigned short* Wswz2 = Wswz1 + (size_t)3 * F * F;
    float* pooledp = (float*)(Wswz2 + (size_t)3 * F * F);             // [4][64][128]

    // prep: cast X + shuffle weights + zero cnt (no in-graph memsets)
    prep_kernel<<<1408, 256, 0, stream>>>(X, P0, P1, W1, W2, Wswz1, Wswz2, (uint4*)cnt4);

    // edge-count scatter (nibbles)
    cnt_scatter_kernel<<<(E + 255) / 256, 256, 0, stream>>>(srcv, dstv, cnt4, E);

    // layer 1: t1c = S@X ; h1 = relu(X@W0 + t1@W1 + (S@t1)@W2 + b1)
    sapply_kernel<<<Bg * 4, 512, 0, stream>>>(cnt4, alpha, P1, P3);
    fused_conv_kernel<1><<<Bg * 4, 512, 0, stream>>>(cnt4, alpha, P3, P0, Wswz1, b1, P0, P1, nullptr);

    // layer 2: u1c = S@h1 ; pooledp = blockwise colmax(relu(h1@W0 + u1@W1 + (S@u1)@W2 + b2))
    sapply_kernel<<<Bg * 4, 512, 0, stream>>>(cnt4, alpha, P1, P3);
    fused_conv_kernel<0><<<Bg * 4, 512, 0, stream>>>(cnt4, alpha, P3, P0, Wswz2, b2, nullptr, nullptr, pooledp);

    // head
    out_gemm_kernel<<<Bg, 64, 0, stream>>>(pooledp, Wout, bout, (float*)d_out);
}